// Round 1
// baseline (5637.012 us; speedup 1.0000x reference)
//
#include <hip/hip_runtime.h>
#include <hip/hip_bf16.h>

#define NODES 100000
#define INC 128
#define HIDC 128
#define EMBC 64
#define PREDH 256

// ---------------- degree ----------------
__global__ void k_deg(const int* __restrict__ ei, int* __restrict__ deg, int E) {
    int e = blockIdx.x * 256 + threadIdx.x;
    if (e >= E) return;
    int d = ei[E + e];           // dst row
    atomicAdd(&deg[d], 1);
}

__global__ void k_dinv(const int* __restrict__ deg, float* __restrict__ dinv, int n) {
    int i = blockIdx.x * 256 + threadIdx.x;
    if (i >= n) return;
    float c = (float)(deg[i] + 1);   // +1 self loop
    dinv[i] = 1.0f / sqrtf(c);
}

// ---------------- dense matmul: O[M,N] = X[M,128] @ W[128,N] ----------------
template <int N>
__global__ __launch_bounds__(256) void k_mm(const float* __restrict__ X,
                                            const float* __restrict__ W,
                                            float* __restrict__ O, int M) {
    __shared__ float Wl[128 * N];
    __shared__ float xs[64 * 129];
    int tid = threadIdx.x;
    int row0 = blockIdx.x * 64;
    for (int i = tid; i < 128 * N; i += 256) Wl[i] = W[i];
    int nrow = min(64, M - row0);
    for (int i = tid; i < nrow * 128; i += 256) {
        int r = i >> 7, k = i & 127;
        xs[r * 129 + k] = X[(size_t)(row0 + r) * 128 + k];
    }
    __syncthreads();
    int row = tid & 63;
    int cg = tid >> 6;            // 0..3
    const int NC = N / 4;         // cols per thread
    int c0 = cg * NC;
    float acc[NC];
#pragma unroll
    for (int j = 0; j < NC; j++) acc[j] = 0.f;
    if (row < nrow) {
        for (int k = 0; k < 128; k++) {
            float xv = xs[row * 129 + k];
            const float4* w4 = reinterpret_cast<const float4*>(&Wl[k * N + c0]);
#pragma unroll
            for (int j = 0; j < NC / 4; j++) {
                float4 w = w4[j];
                acc[4 * j + 0] += xv * w.x;
                acc[4 * j + 1] += xv * w.y;
                acc[4 * j + 2] += xv * w.z;
                acc[4 * j + 3] += xv * w.w;
            }
        }
        float4* o4 = reinterpret_cast<float4*>(&O[(size_t)(row0 + row) * N + c0]);
#pragma unroll
        for (int j = 0; j < NC / 4; j++)
            o4[j] = make_float4(acc[4 * j], acc[4 * j + 1], acc[4 * j + 2], acc[4 * j + 3]);
    }
}

// ---------------- AGG = H * dinv^2 (self-loop init) ----------------
template <int LOG2C>
__global__ void k_selfinit(const float* __restrict__ H, const float* __restrict__ dinv,
                           float* __restrict__ A, int total4) {
    int idx = blockIdx.x * 256 + threadIdx.x;
    if (idx >= total4) return;
    int row = (idx * 4) >> LOG2C;
    float di = dinv[row];
    float s = di * di;
    float4 h = ((const float4*)H)[idx];
    ((float4*)A)[idx] = make_float4(h.x * s, h.y * s, h.z * s, h.w * s);
}

// ---------------- edge scatter: AGG[dst] += H[src] * dinv[src]*dinv[dst] ----------------
template <int C>
__global__ void k_agg(const float* __restrict__ H, const float* __restrict__ dinv,
                      const int* __restrict__ ei, float* __restrict__ AGG, int E) {
    const int TPE = C / 4;
    int gid = blockIdx.x * 256 + threadIdx.x;
    int e = gid / TPE;
    int c4 = gid % TPE;
    if (e >= E) return;
    int s = ei[e];
    int d = ei[E + e];
    float coef = dinv[s] * dinv[d];
    float4 h = ((const float4*)(H + (size_t)s * C))[c4];
    float* a = AGG + (size_t)d * C + c4 * 4;
    atomicAdd(a + 0, h.x * coef);
    atomicAdd(a + 1, h.y * coef);
    atomicAdd(a + 2, h.z * coef);
    atomicAdd(a + 3, h.w * coef);
}

// ---------------- O = (AGG + b) [relu] ----------------
template <int C, bool RELU>
__global__ void k_post(const float* __restrict__ A, const float* __restrict__ b,
                       float* __restrict__ O, int total4) {
    int idx = blockIdx.x * 256 + threadIdx.x;
    if (idx >= total4) return;
    int c = (idx * 4) & (C - 1);
    float4 a = ((const float4*)A)[idx];
    float4 bb = *(const float4*)(b + c);
    float4 r = make_float4(a.x + bb.x, a.y + bb.y, a.z + bb.z, a.w + bb.w);
    if (RELU) {
        r.x = fmaxf(r.x, 0.f);
        r.y = fmaxf(r.y, 0.f);
        r.z = fmaxf(r.z, 0.f);
        r.w = fmaxf(r.w, 0.f);
    }
    ((float4*)O)[idx] = r;
}

// ---------------- fused link-prediction MLP ----------------
// block: 256 threads, 64 pairs. pf[64][256] staged in LDS; Wm1 in 4 col tiles of 64.
__global__ __launch_bounds__(256) void k_pred(const float* __restrict__ Z,       // [NODES, 64]
                                              const int* __restrict__ eli,       // [2, P]
                                              const float* __restrict__ Wm1,     // [256,256]
                                              const float* __restrict__ bm1,     // [256]
                                              const float* __restrict__ Wm2,     // [256]
                                              const float* __restrict__ bm2,     // [1]
                                              float* __restrict__ out, int P) {
    __shared__ float pf[64 * 257];
    __shared__ float wt[256 * 64];
    int tid = threadIdx.x;
    int p0 = blockIdx.x * 64;
    for (int i = tid; i < 64 * 256; i += 256) {
        int pr = i >> 8, c = i & 255;
        int pg = p0 + pr;
        float v = 0.f;
        if (pg < P) {
            int s = eli[pg], d = eli[P + pg];
            int cc = c & 63, q = c >> 6;
            float zs = Z[(size_t)s * 64 + cc];
            float zd = Z[(size_t)d * 64 + cc];
            v = (q == 0) ? zs : (q == 1) ? zd : (q == 2) ? zs * zd : fabsf(zs - zd);
        }
        pf[pr * 257 + c] = v;
    }
    int pr = tid >> 2;   // 0..63 pair within block
    int cs = tid & 3;    // 0..3 col sub-group
    float plog = 0.f;
    for (int t = 0; t < 4; ++t) {
        __syncthreads();
        for (int i = tid; i < 256 * 64; i += 256) {
            int k = i >> 6, c = i & 63;
            wt[i] = Wm1[k * 256 + t * 64 + c];
        }
        __syncthreads();
        float acc[16];
#pragma unroll
        for (int j = 0; j < 16; j++) acc[j] = 0.f;
        for (int k = 0; k < 256; k++) {
            float pfv = pf[pr * 257 + k];
            const float4* w4 = (const float4*)&wt[k * 64 + cs * 16];
#pragma unroll
            for (int j = 0; j < 4; j++) {
                float4 w = w4[j];
                acc[4 * j + 0] += pfv * w.x;
                acc[4 * j + 1] += pfv * w.y;
                acc[4 * j + 2] += pfv * w.z;
                acc[4 * j + 3] += pfv * w.w;
            }
        }
#pragma unroll
        for (int j = 0; j < 16; j++) {
            int c = t * 64 + cs * 16 + j;
            float hm = fmaxf(acc[j] + bm1[c], 0.f);
            plog += hm * Wm2[c];
        }
    }
    plog += __shfl_xor(plog, 1);
    plog += __shfl_xor(plog, 2);
    int pg = p0 + pr;
    if (cs == 0 && pg < P) out[pg] = plog + bm2[0];
}

extern "C" void kernel_launch(void* const* d_in, const int* in_sizes, int n_in,
                              void* d_out, int out_size, void* d_ws, size_t ws_size,
                              hipStream_t stream) {
    const float* x   = (const float*)d_in[0];
    const int*   ei  = (const int*)d_in[1];
    const int*   eli = (const int*)d_in[2];
    const float* W1  = (const float*)d_in[3];
    const float* b1  = (const float*)d_in[4];
    const float* W2  = (const float*)d_in[5];
    const float* b2  = (const float*)d_in[6];
    const float* Wm1 = (const float*)d_in[7];
    const float* bm1 = (const float*)d_in[8];
    const float* Wm2 = (const float*)d_in[9];
    const float* bm2 = (const float*)d_in[10];
    float* out = (float*)d_out;

    const int n = NODES;
    const int E = in_sizes[1] / 2;
    const int P = in_sizes[2] / 2;

    char* ws = (char*)d_ws;
    size_t off = 0;
    auto alloc = [&](size_t bytes) {
        size_t o = off;
        off += (bytes + 255) & ~(size_t)255;
        return o;
    };
    int*   deg  = (int*)(ws + alloc((size_t)n * 4));
    float* dinv = (float*)(ws + alloc((size_t)n * 4));
    float* H1   = (float*)(ws + alloc((size_t)n * HIDC * 4));   // x@W1, later relu'd conv1 out
    float* AGG1 = (float*)(ws + alloc((size_t)n * HIDC * 4));
    float* H2   = (float*)(ws + alloc((size_t)n * EMBC * 4));   // h@W2, later Z
    float* AGG2 = (float*)(ws + alloc((size_t)n * EMBC * 4));

    // degree + dinv
    hipMemsetAsync(deg, 0, (size_t)n * 4, stream);
    k_deg<<<(E + 255) / 256, 256, 0, stream>>>(ei, deg, E);
    k_dinv<<<(n + 255) / 256, 256, 0, stream>>>(deg, dinv, n);

    int mmGrid = (n + 63) / 64;

    // conv1
    k_mm<HIDC><<<mmGrid, 256, 0, stream>>>(x, W1, H1, n);
    int t4_1 = n * HIDC / 4;
    k_selfinit<7><<<(t4_1 + 255) / 256, 256, 0, stream>>>(H1, dinv, AGG1, t4_1);
    {
        int total = E * (HIDC / 4);
        k_agg<HIDC><<<(total + 255) / 256, 256, 0, stream>>>(H1, dinv, ei, AGG1, E);
    }
    k_post<HIDC, true><<<(t4_1 + 255) / 256, 256, 0, stream>>>(AGG1, b1, H1, t4_1);

    // conv2
    k_mm<EMBC><<<mmGrid, 256, 0, stream>>>(H1, W2, H2, n);
    int t4_2 = n * EMBC / 4;
    k_selfinit<6><<<(t4_2 + 255) / 256, 256, 0, stream>>>(H2, dinv, AGG2, t4_2);
    {
        int total = E * (EMBC / 4);
        k_agg<EMBC><<<(total + 255) / 256, 256, 0, stream>>>(H2, dinv, ei, AGG2, E);
    }
    k_post<EMBC, false><<<(t4_2 + 255) / 256, 256, 0, stream>>>(AGG2, b2, H2, t4_2);

    // prediction head (reads H2 as Z)
    k_pred<<<(P + 63) / 64, 256, 0, stream>>>(H2, eli, Wm1, bm1, Wm2, bm2, out, P);
}

// Round 2
// 1886.002 us; speedup vs baseline: 2.9889x; 2.9889x over previous
//
#include <hip/hip_runtime.h>
#include <hip/hip_bf16.h>

#define NODES 100000
#define INC 128
#define HIDC 128
#define EMBC 64
#define PREDH 256

// ---------------- degree (incoming, excl. self loop) ----------------
__global__ void k_deg(const int* __restrict__ ei, int* __restrict__ deg, int E) {
    int e = blockIdx.x * 256 + threadIdx.x;
    if (e >= E) return;
    atomicAdd(&deg[ei[E + e]], 1);
}

__global__ void k_dinv(const int* __restrict__ deg, float* __restrict__ dinv, int n) {
    int i = blockIdx.x * 256 + threadIdx.x;
    if (i >= n) return;
    float c = (float)(deg[i] + 1);   // +1 self loop
    dinv[i] = 1.0f / sqrtf(c);
}

// ---------------- exclusive scan (3 kernels) ----------------
__global__ __launch_bounds__(1024) void k_scan1(const int* __restrict__ deg,
                                                int* __restrict__ rowptr,
                                                int* __restrict__ bsum, int n) {
    __shared__ int tmp[1024];
    int tid = threadIdx.x;
    int i = blockIdx.x * 1024 + tid;
    int v = (i < n) ? deg[i] : 0;
    tmp[tid] = v;
    __syncthreads();
    for (int off = 1; off < 1024; off <<= 1) {
        int t = (tid >= off) ? tmp[tid - off] : 0;
        __syncthreads();
        tmp[tid] += t;
        __syncthreads();
    }
    if (i < n) rowptr[i] = tmp[tid] - v;          // exclusive
    if (tid == 1023) bsum[blockIdx.x] = tmp[1023];
}

__global__ __launch_bounds__(128) void k_scan2(int* __restrict__ bsum, int nb) {
    __shared__ int tmp[128];
    int tid = threadIdx.x;
    int v = (tid < nb) ? bsum[tid] : 0;
    tmp[tid] = v;
    __syncthreads();
    for (int off = 1; off < 128; off <<= 1) {
        int t = (tid >= off) ? tmp[tid - off] : 0;
        __syncthreads();
        tmp[tid] += t;
        __syncthreads();
    }
    if (tid < nb) bsum[tid] = tmp[tid] - v;       // exclusive block offsets
}

__global__ __launch_bounds__(1024) void k_scan3(int* __restrict__ rowptr, int* __restrict__ cur,
                                                const int* __restrict__ bsum, int n) {
    int i = blockIdx.x * 1024 + threadIdx.x;
    if (i >= n) return;
    int r = rowptr[i] + bsum[blockIdx.x];
    rowptr[i] = r;
    cur[i] = r;
}

// ---------------- CSR fill (dst-grouped src list) ----------------
__global__ void k_fill(const int* __restrict__ ei, int* __restrict__ cur,
                       int* __restrict__ col, int E) {
    int e = blockIdx.x * 256 + threadIdx.x;
    if (e >= E) return;
    int s = ei[e], d = ei[E + e];
    int pos = atomicAdd(&cur[d], 1);
    col[pos] = s;
}

// ---------------- dense matmul: O[M,N] = X[M,128] @ W[128,N] ----------------
template <int N>
__global__ __launch_bounds__(256) void k_mm(const float* __restrict__ X,
                                            const float* __restrict__ W,
                                            float* __restrict__ O, int M) {
    __shared__ float Wl[128 * N];
    __shared__ float xs[64 * 129];
    int tid = threadIdx.x;
    int row0 = blockIdx.x * 64;
    for (int i = tid; i < 128 * N; i += 256) Wl[i] = W[i];
    int nrow = min(64, M - row0);
    for (int i = tid; i < nrow * 128; i += 256) {
        int r = i >> 7, k = i & 127;
        xs[r * 129 + k] = X[(size_t)(row0 + r) * 128 + k];
    }
    __syncthreads();
    int row = tid & 63;
    int cg = tid >> 6;            // 0..3
    const int NC = N / 4;         // cols per thread
    int c0 = cg * NC;
    float acc[NC];
#pragma unroll
    for (int j = 0; j < NC; j++) acc[j] = 0.f;
    if (row < nrow) {
        for (int k = 0; k < 128; k++) {
            float xv = xs[row * 129 + k];
            const float4* w4 = reinterpret_cast<const float4*>(&Wl[k * N + c0]);
#pragma unroll
            for (int j = 0; j < NC / 4; j++) {
                float4 w = w4[j];
                acc[4 * j + 0] += xv * w.x;
                acc[4 * j + 1] += xv * w.y;
                acc[4 * j + 2] += xv * w.z;
                acc[4 * j + 3] += xv * w.w;
            }
        }
        float4* o4 = reinterpret_cast<float4*>(&O[(size_t)(row0 + row) * N + c0]);
#pragma unroll
        for (int j = 0; j < NC / 4; j++)
            o4[j] = make_float4(acc[4 * j], acc[4 * j + 1], acc[4 * j + 2], acc[4 * j + 3]);
    }
}

// ---------------- fused gather aggregation + self loop + bias (+relu) ----------------
// O[d] = relu( dinv[d] * ( sum_{s in N(d)} H[s]*dinv[s] + H[d]*dinv[d] ) + b )
template <int C, bool RELU>
__global__ __launch_bounds__(256) void k_gather(const float* __restrict__ H,
                                                const float* __restrict__ dinv,
                                                const int* __restrict__ rowptr,
                                                const int* __restrict__ deg,
                                                const int* __restrict__ col,
                                                const float* __restrict__ b,
                                                float* __restrict__ O, int n) {
    const int TPN = C / 2;                  // threads per node, float2 each
    const int NPB = 256 / TPN;
    int node = blockIdx.x * NPB + threadIdx.x / TPN;
    int lane = threadIdx.x % TPN;
    if (node >= n) return;
    int start = rowptr[node];
    int cnt = deg[node];
    float dd = dinv[node];
    float2 h = ((const float2*)(H + (size_t)node * C))[lane];
    float2 acc = make_float2(h.x * dd, h.y * dd);     // self-loop term (×dd again below)
    for (int j = 0; j < cnt; ++j) {
        int s = col[start + j];
        float ds = dinv[s];
        float2 hs = ((const float2*)(H + (size_t)s * C))[lane];
        acc.x += hs.x * ds;
        acc.y += hs.y * ds;
    }
    float2 bb = ((const float2*)b)[lane];
    float vx = acc.x * dd + bb.x;
    float vy = acc.y * dd + bb.y;
    if (RELU) { vx = fmaxf(vx, 0.f); vy = fmaxf(vy, 0.f); }
    ((float2*)(O + (size_t)node * C))[lane] = make_float2(vx, vy);
}

// ---------------- fused link-prediction MLP ----------------
__global__ __launch_bounds__(256) void k_pred(const float* __restrict__ Z,       // [NODES, 64]
                                              const int* __restrict__ eli,       // [2, P]
                                              const float* __restrict__ Wm1,     // [256,256]
                                              const float* __restrict__ bm1,     // [256]
                                              const float* __restrict__ Wm2,     // [256]
                                              const float* __restrict__ bm2,     // [1]
                                              float* __restrict__ out, int P) {
    __shared__ float pf[64 * 257];
    __shared__ float wt[256 * 64];
    int tid = threadIdx.x;
    int p0 = blockIdx.x * 64;
    for (int i = tid; i < 64 * 256; i += 256) {
        int pr = i >> 8, c = i & 255;
        int pg = p0 + pr;
        float v = 0.f;
        if (pg < P) {
            int s = eli[pg], d = eli[P + pg];
            int cc = c & 63, q = c >> 6;
            float zs = Z[(size_t)s * 64 + cc];
            float zd = Z[(size_t)d * 64 + cc];
            v = (q == 0) ? zs : (q == 1) ? zd : (q == 2) ? zs * zd : fabsf(zs - zd);
        }
        pf[pr * 257 + c] = v;
    }
    int pr = tid >> 2;   // 0..63 pair within block
    int cs = tid & 3;    // 0..3 col sub-group
    float plog = 0.f;
    for (int t = 0; t < 4; ++t) {
        __syncthreads();
        for (int i = tid; i < 256 * 64; i += 256) {
            int k = i >> 6, c = i & 63;
            wt[i] = Wm1[k * 256 + t * 64 + c];
        }
        __syncthreads();
        float acc[16];
#pragma unroll
        for (int j = 0; j < 16; j++) acc[j] = 0.f;
        for (int k = 0; k < 256; k++) {
            float pfv = pf[pr * 257 + k];
            const float4* w4 = (const float4*)&wt[k * 64 + cs * 16];
#pragma unroll
            for (int j = 0; j < 4; j++) {
                float4 w = w4[j];
                acc[4 * j + 0] += pfv * w.x;
                acc[4 * j + 1] += pfv * w.y;
                acc[4 * j + 2] += pfv * w.z;
                acc[4 * j + 3] += pfv * w.w;
            }
        }
#pragma unroll
        for (int j = 0; j < 16; j++) {
            int c = t * 64 + cs * 16 + j;
            float hm = fmaxf(acc[j] + bm1[c], 0.f);
            plog += hm * Wm2[c];
        }
    }
    plog += __shfl_xor(plog, 1);
    plog += __shfl_xor(plog, 2);
    int pg = p0 + pr;
    if (cs == 0 && pg < P) out[pg] = plog + bm2[0];
}

extern "C" void kernel_launch(void* const* d_in, const int* in_sizes, int n_in,
                              void* d_out, int out_size, void* d_ws, size_t ws_size,
                              hipStream_t stream) {
    const float* x   = (const float*)d_in[0];
    const int*   ei  = (const int*)d_in[1];
    const int*   eli = (const int*)d_in[2];
    const float* W1  = (const float*)d_in[3];
    const float* b1  = (const float*)d_in[4];
    const float* W2  = (const float*)d_in[5];
    const float* b2  = (const float*)d_in[6];
    const float* Wm1 = (const float*)d_in[7];
    const float* bm1 = (const float*)d_in[8];
    const float* Wm2 = (const float*)d_in[9];
    const float* bm2 = (const float*)d_in[10];
    float* out = (float*)d_out;

    const int n = NODES;
    const int E = in_sizes[1] / 2;
    const int P = in_sizes[2] / 2;

    char* ws = (char*)d_ws;
    size_t off = 0;
    auto alloc = [&](size_t bytes) {
        size_t o = off;
        off += (bytes + 255) & ~(size_t)255;
        return o;
    };
    int*   deg    = (int*)(ws + alloc((size_t)n * 4));
    int*   rowptr = (int*)(ws + alloc((size_t)n * 4));
    int*   cur    = (int*)(ws + alloc((size_t)n * 4));
    int*   colx   = (int*)(ws + alloc((size_t)E * 4));
    int*   bsum   = (int*)(ws + alloc(512 * 4));
    float* dinv   = (float*)(ws + alloc((size_t)n * 4));
    float* H1     = (float*)(ws + alloc((size_t)n * HIDC * 4));  // x@W1
    float* C1     = (float*)(ws + alloc((size_t)n * HIDC * 4));  // conv1 out
    float* H2     = (float*)(ws + alloc((size_t)n * EMBC * 4));  // C1@W2
    float* Z      = (float*)(ws + alloc((size_t)n * EMBC * 4));  // conv2 out

    // ---- CSR build ----
    hipMemsetAsync(deg, 0, (size_t)n * 4, stream);
    k_deg<<<(E + 255) / 256, 256, 0, stream>>>(ei, deg, E);
    int nb = (n + 1023) / 1024;
    k_scan1<<<nb, 1024, 0, stream>>>(deg, rowptr, bsum, n);
    k_scan2<<<1, 128, 0, stream>>>(bsum, nb);
    k_scan3<<<nb, 1024, 0, stream>>>(rowptr, cur, bsum, n);
    k_fill<<<(E + 255) / 256, 256, 0, stream>>>(ei, cur, colx, E);
    k_dinv<<<(n + 255) / 256, 256, 0, stream>>>(deg, dinv, n);

    int mmGrid = (n + 63) / 64;

    // ---- conv1 ----
    k_mm<HIDC><<<mmGrid, 256, 0, stream>>>(x, W1, H1, n);
    {
        const int NPB = 256 / (HIDC / 2);   // 4 nodes per block
        k_gather<HIDC, true><<<(n + NPB - 1) / NPB, 256, 0, stream>>>(
            H1, dinv, rowptr, deg, colx, b1, C1, n);
    }

    // ---- conv2 ----
    k_mm<EMBC><<<mmGrid, 256, 0, stream>>>(C1, W2, H2, n);
    {
        const int NPB = 256 / (EMBC / 2);   // 8 nodes per block
        k_gather<EMBC, false><<<(n + NPB - 1) / NPB, 256, 0, stream>>>(
            H2, dinv, rowptr, deg, colx, b2, Z, n);
    }

    // ---- prediction head ----
    k_pred<<<(P + 63) / 64, 256, 0, stream>>>(Z, eli, Wm1, bm1, Wm2, bm2, out, P);
}

// Round 4
// 793.854 us; speedup vs baseline: 7.1008x; 2.3758x over previous
//
#include <hip/hip_runtime.h>
#include <hip/hip_bf16.h>
#include <hip/hip_fp16.h>

#define NODES 100000
#define INC 128
#define HIDC 128
#define EMBC 64
#define PREDH 256

typedef __attribute__((ext_vector_type(8))) _Float16 half8;
typedef __attribute__((ext_vector_type(4))) float f32x4;

// ---------------- degree (incoming, excl. self loop) ----------------
__global__ void k_deg(const int* __restrict__ ei, int* __restrict__ deg, int E) {
    int e = blockIdx.x * 256 + threadIdx.x;
    if (e >= E) return;
    atomicAdd(&deg[ei[E + e]], 1);
}

__global__ void k_dinv(const int* __restrict__ deg, float* __restrict__ dinv, int n) {
    int i = blockIdx.x * 256 + threadIdx.x;
    if (i >= n) return;
    float c = (float)(deg[i] + 1);   // +1 self loop
    dinv[i] = 1.0f / sqrtf(c);
}

// ---------------- exclusive scan (3 kernels) ----------------
__global__ __launch_bounds__(1024) void k_scan1(const int* __restrict__ deg,
                                                int* __restrict__ rowptr,
                                                int* __restrict__ bsum, int n) {
    __shared__ int tmp[1024];
    int tid = threadIdx.x;
    int i = blockIdx.x * 1024 + tid;
    int v = (i < n) ? deg[i] : 0;
    tmp[tid] = v;
    __syncthreads();
    for (int off = 1; off < 1024; off <<= 1) {
        int t = (tid >= off) ? tmp[tid - off] : 0;
        __syncthreads();
        tmp[tid] += t;
        __syncthreads();
    }
    if (i < n) rowptr[i] = tmp[tid] - v;          // exclusive
    if (tid == 1023) bsum[blockIdx.x] = tmp[1023];
}

__global__ __launch_bounds__(128) void k_scan2(int* __restrict__ bsum, int nb) {
    __shared__ int tmp[128];
    int tid = threadIdx.x;
    int v = (tid < nb) ? bsum[tid] : 0;
    tmp[tid] = v;
    __syncthreads();
    for (int off = 1; off < 128; off <<= 1) {
        int t = (tid >= off) ? tmp[tid - off] : 0;
        __syncthreads();
        tmp[tid] += t;
        __syncthreads();
    }
    if (tid < nb) bsum[tid] = tmp[tid] - v;       // exclusive block offsets
}

__global__ __launch_bounds__(1024) void k_scan3(int* __restrict__ rowptr, int* __restrict__ cur,
                                                const int* __restrict__ bsum, int n) {
    int i = blockIdx.x * 1024 + threadIdx.x;
    if (i >= n) return;
    int r = rowptr[i] + bsum[blockIdx.x];
    rowptr[i] = r;
    cur[i] = r;
}

// ---------------- CSR fill (dst-grouped src list) ----------------
__global__ void k_fill(const int* __restrict__ ei, int* __restrict__ cur,
                       int* __restrict__ col, int E) {
    int e = blockIdx.x * 256 + threadIdx.x;
    if (e >= E) return;
    int s = ei[e], d = ei[E + e];
    int pos = atomicAdd(&cur[d], 1);
    col[pos] = s;
}

// ---------------- Wm1 [256,256] -> Wm1T f16 [n][k] ----------------
__global__ void k_prepw(const float* __restrict__ Wm1, _Float16* __restrict__ WT) {
    int i = blockIdx.x * 256 + threadIdx.x;
    if (i >= 256 * 256) return;
    int n = i >> 8, k = i & 255;
    WT[n * 256 + k] = (_Float16)Wm1[k * 256 + n];
}

// ---------------- dense matmul: O[M,N] = X[M,128] @ W[128,N] ----------------
template <int N>
__global__ __launch_bounds__(256) void k_mm(const float* __restrict__ X,
                                            const float* __restrict__ W,
                                            float* __restrict__ O, int M) {
    __shared__ float Wl[128 * N];
    __shared__ float xs[64 * 129];
    int tid = threadIdx.x;
    int row0 = blockIdx.x * 64;
    for (int i = tid; i < 128 * N; i += 256) Wl[i] = W[i];
    int nrow = min(64, M - row0);
    for (int i = tid; i < nrow * 128; i += 256) {
        int r = i >> 7, k = i & 127;
        xs[r * 129 + k] = X[(size_t)(row0 + r) * 128 + k];
    }
    __syncthreads();
    int row = tid & 63;
    int cg = tid >> 6;            // 0..3
    const int NC = N / 4;         // cols per thread
    int c0 = cg * NC;
    float acc[NC];
#pragma unroll
    for (int j = 0; j < NC; j++) acc[j] = 0.f;
    if (row < nrow) {
        for (int k = 0; k < 128; k++) {
            float xv = xs[row * 129 + k];
            const float4* w4 = reinterpret_cast<const float4*>(&Wl[k * N + c0]);
#pragma unroll
            for (int j = 0; j < NC / 4; j++) {
                float4 w = w4[j];
                acc[4 * j + 0] += xv * w.x;
                acc[4 * j + 1] += xv * w.y;
                acc[4 * j + 2] += xv * w.z;
                acc[4 * j + 3] += xv * w.w;
            }
        }
        float4* o4 = reinterpret_cast<float4*>(&O[(size_t)(row0 + row) * N + c0]);
#pragma unroll
        for (int j = 0; j < NC / 4; j++)
            o4[j] = make_float4(acc[4 * j], acc[4 * j + 1], acc[4 * j + 2], acc[4 * j + 3]);
    }
}

// ---------------- fused gather aggregation + self loop + bias (+relu) ----------------
template <int C, bool RELU>
__global__ __launch_bounds__(256) void k_gather(const float* __restrict__ H,
                                                const float* __restrict__ dinv,
                                                const int* __restrict__ rowptr,
                                                const int* __restrict__ deg,
                                                const int* __restrict__ col,
                                                const float* __restrict__ b,
                                                float* __restrict__ O, int n) {
    const int TPN = C / 2;                  // threads per node, float2 each
    const int NPB = 256 / TPN;
    int node = blockIdx.x * NPB + threadIdx.x / TPN;
    int lane = threadIdx.x % TPN;
    if (node >= n) return;
    int start = rowptr[node];
    int cnt = deg[node];
    float dd = dinv[node];
    float2 h = ((const float2*)(H + (size_t)node * C))[lane];
    float2 acc = make_float2(h.x * dd, h.y * dd);     // self-loop term (×dd again below)
    for (int j = 0; j < cnt; ++j) {
        int s = col[start + j];
        float ds = dinv[s];
        float2 hs = ((const float2*)(H + (size_t)s * C))[lane];
        acc.x += hs.x * ds;
        acc.y += hs.y * ds;
    }
    float2 bb = ((const float2*)b)[lane];
    float vx = acc.x * dd + bb.x;
    float vy = acc.y * dd + bb.y;
    if (RELU) { vx = fmaxf(vx, 0.f); vy = fmaxf(vy, 0.f); }
    ((float2*)(O + (size_t)node * C))[lane] = make_float2(vx, vy);
}

// ---------------- MFMA link-prediction head ----------------
// 64 pairs per block, 4 waves; wave w owns N-cols [w*64, w*64+64).
// pf[64][256] f16 in LDS (pad->264). Layer1 via mfma_f32_16x16x32_f16,
// layer2 (relu+dot Wm2) fused in epilogue with shfl butterfly.
__global__ __launch_bounds__(256) void k_predm(const float* __restrict__ Z,      // [NODES,64] f32
                                               const int* __restrict__ eli,      // [2,P]
                                               const _Float16* __restrict__ WT,  // [256n][256k]
                                               const float* __restrict__ bm1,
                                               const float* __restrict__ Wm2,
                                               const float* __restrict__ bm2,
                                               float* __restrict__ out, int P) {
    __shared__ _Float16 pf[64][264];   // ~33.8 KB
    __shared__ float red[4][64];
    int tid = threadIdx.x;
    int p0 = blockIdx.x * 64;

    // ---- build pf features (f32 compute, f16 store) ----
    {
        int pr = tid >> 2, q = tid & 3;       // 4 threads/pair, 16 cols each
        int pg = p0 + pr;
        int s = 0, d = 0;
        if (pg < P) { s = eli[pg]; d = eli[P + pg]; }
        const float4* zs4 = (const float4*)(Z + (size_t)s * 64 + q * 16);
        const float4* zd4 = (const float4*)(Z + (size_t)d * 64 + q * 16);
#pragma unroll
        for (int j = 0; j < 4; ++j) {
            float4 a = zs4[j], b = zd4[j];
            int c = q * 16 + j * 4;
            pf[pr][c + 0] = (_Float16)a.x;
            pf[pr][c + 1] = (_Float16)a.y;
            pf[pr][c + 2] = (_Float16)a.z;
            pf[pr][c + 3] = (_Float16)a.w;
            pf[pr][64 + c + 0] = (_Float16)b.x;
            pf[pr][64 + c + 1] = (_Float16)b.y;
            pf[pr][64 + c + 2] = (_Float16)b.z;
            pf[pr][64 + c + 3] = (_Float16)b.w;
            pf[pr][128 + c + 0] = (_Float16)(a.x * b.x);
            pf[pr][128 + c + 1] = (_Float16)(a.y * b.y);
            pf[pr][128 + c + 2] = (_Float16)(a.z * b.z);
            pf[pr][128 + c + 3] = (_Float16)(a.w * b.w);
            pf[pr][192 + c + 0] = (_Float16)fabsf(a.x - b.x);
            pf[pr][192 + c + 1] = (_Float16)fabsf(a.y - b.y);
            pf[pr][192 + c + 2] = (_Float16)fabsf(a.z - b.z);
            pf[pr][192 + c + 3] = (_Float16)fabsf(a.w - b.w);
        }
    }
    __syncthreads();

    int wid = tid >> 6, lane = tid & 63;
    int lr = lane & 15, kg = lane >> 4;
    int n0 = wid * 64;

    // per-lane layer-2 constants for my 4 n-columns
    float wmv[4], bmv[4];
#pragma unroll
    for (int nr = 0; nr < 4; nr++) {
        int nn = n0 + nr * 16 + lr;
        wmv[nr] = Wm2[nn];
        bmv[nr] = bm1[nn];
    }

    f32x4 acc[4][4];
#pragma unroll
    for (int mr = 0; mr < 4; mr++)
#pragma unroll
        for (int nr = 0; nr < 4; nr++) acc[mr][nr] = (f32x4){0.f, 0.f, 0.f, 0.f};

    // ---- layer-1 GEMM: K=256 in 8 steps of 32 ----
    for (int ks = 0; ks < 8; ks++) {
        half8 a[4], b[4];
#pragma unroll
        for (int mr = 0; mr < 4; mr++)
            a[mr] = *(const half8*)&pf[mr * 16 + lr][ks * 32 + kg * 8];
#pragma unroll
        for (int nr = 0; nr < 4; nr++)
            b[nr] = *(const half8*)&WT[(size_t)(n0 + nr * 16 + lr) * 256 + ks * 32 + kg * 8];
#pragma unroll
        for (int mr = 0; mr < 4; mr++)
#pragma unroll
            for (int nr = 0; nr < 4; nr++)
                acc[mr][nr] = __builtin_amdgcn_mfma_f32_16x16x32_f16(a[mr], b[nr], acc[mr][nr], 0, 0, 0);
    }

    // ---- layer 2: relu(acc + bm1) . Wm2, reduce over n ----
#pragma unroll
    for (int mr = 0; mr < 4; mr++) {
#pragma unroll
        for (int reg = 0; reg < 4; reg++) {
            float p = 0.f;
#pragma unroll
            for (int nr = 0; nr < 4; nr++)
                p += fmaxf(acc[mr][nr][reg] + bmv[nr], 0.f) * wmv[nr];
            p += __shfl_xor(p, 1);
            p += __shfl_xor(p, 2);
            p += __shfl_xor(p, 4);
            p += __shfl_xor(p, 8);
            if (lr == 0) red[wid][mr * 16 + kg * 4 + reg] = p;
        }
    }
    __syncthreads();
    if (tid < 64) {
        int pg = p0 + tid;
        if (pg < P)
            out[pg] = red[0][tid] + red[1][tid] + red[2][tid] + red[3][tid] + bm2[0];
    }
}

extern "C" void kernel_launch(void* const* d_in, const int* in_sizes, int n_in,
                              void* d_out, int out_size, void* d_ws, size_t ws_size,
                              hipStream_t stream) {
    const float* x   = (const float*)d_in[0];
    const int*   ei  = (const int*)d_in[1];
    const int*   eli = (const int*)d_in[2];
    const float* W1  = (const float*)d_in[3];
    const float* b1  = (const float*)d_in[4];
    const float* W2  = (const float*)d_in[5];
    const float* b2  = (const float*)d_in[6];
    const float* Wm1 = (const float*)d_in[7];
    const float* bm1 = (const float*)d_in[8];
    const float* Wm2 = (const float*)d_in[9];
    const float* bm2 = (const float*)d_in[10];
    float* out = (float*)d_out;

    const int n = NODES;
    const int E = in_sizes[1] / 2;
    const int P = in_sizes[2] / 2;

    char* ws = (char*)d_ws;
    size_t off = 0;
    auto alloc = [&](size_t bytes) {
        size_t o = off;
        off += (bytes + 255) & ~(size_t)255;
        return o;
    };
    int*   deg    = (int*)(ws + alloc((size_t)n * 4));
    int*   rowptr = (int*)(ws + alloc((size_t)n * 4));
    int*   cur    = (int*)(ws + alloc((size_t)n * 4));
    int*   colx   = (int*)(ws + alloc((size_t)E * 4));
    int*   bsum   = (int*)(ws + alloc(512 * 4));
    float* dinv   = (float*)(ws + alloc((size_t)n * 4));
    _Float16* WT  = (_Float16*)(ws + alloc((size_t)256 * 256 * 2));
    float* H1     = (float*)(ws + alloc((size_t)n * HIDC * 4));  // x@W1
    float* C1     = (float*)(ws + alloc((size_t)n * HIDC * 4));  // conv1 out
    float* H2     = (float*)(ws + alloc((size_t)n * EMBC * 4));  // C1@W2
    float* Z      = (float*)(ws + alloc((size_t)n * EMBC * 4));  // conv2 out

    // ---- CSR build + weight prep ----
    hipMemsetAsync(deg, 0, (size_t)n * 4, stream);
    k_deg<<<(E + 255) / 256, 256, 0, stream>>>(ei, deg, E);
    k_prepw<<<256, 256, 0, stream>>>(Wm1, WT);
    int nb = (n + 1023) / 1024;
    k_scan1<<<nb, 1024, 0, stream>>>(deg, rowptr, bsum, n);
    k_scan2<<<1, 128, 0, stream>>>(bsum, nb);
    k_scan3<<<nb, 1024, 0, stream>>>(rowptr, cur, bsum, n);
    k_fill<<<(E + 255) / 256, 256, 0, stream>>>(ei, cur, colx, E);
    k_dinv<<<(n + 255) / 256, 256, 0, stream>>>(deg, dinv, n);

    int mmGrid = (n + 63) / 64;

    // ---- conv1 ----
    k_mm<HIDC><<<mmGrid, 256, 0, stream>>>(x, W1, H1, n);
    {
        const int NPB = 256 / (HIDC / 2);   // 4 nodes per block
        k_gather<HIDC, true><<<(n + NPB - 1) / NPB, 256, 0, stream>>>(
            H1, dinv, rowptr, deg, colx, b1, C1, n);
    }

    // ---- conv2 ----
    k_mm<EMBC><<<mmGrid, 256, 0, stream>>>(C1, W2, H2, n);
    {
        const int NPB = 256 / (EMBC / 2);   // 8 nodes per block
        k_gather<EMBC, false><<<(n + NPB - 1) / NPB, 256, 0, stream>>>(
            H2, dinv, rowptr, deg, colx, b2, Z, n);
    }

    // ---- prediction head (MFMA f16) ----
    k_predm<<<(P + 63) / 64, 256, 0, stream>>>(Z, eli, WT, bm1, Wm2, bm2, out, P);
}

// Round 5
// 551.358 us; speedup vs baseline: 10.2239x; 1.4398x over previous
//
#include <hip/hip_runtime.h>
#include <hip/hip_bf16.h>
#include <hip/hip_fp16.h>

#define NODES 100000
#define INC 128
#define HIDC 128
#define EMBC 64
#define PREDH 256

typedef __attribute__((ext_vector_type(8))) _Float16 half8;
typedef __attribute__((ext_vector_type(2))) _Float16 half2v;
typedef __attribute__((ext_vector_type(4))) float f32x4;

// ---------------- degree (incoming, excl. self loop) ----------------
__global__ void k_deg(const int* __restrict__ ei, int* __restrict__ deg, int E) {
    int e = blockIdx.x * 256 + threadIdx.x;
    if (e >= E) return;
    atomicAdd(&deg[ei[E + e]], 1);
}

__global__ void k_dinv(const int* __restrict__ deg, float* __restrict__ dinv, int n) {
    int i = blockIdx.x * 256 + threadIdx.x;
    if (i >= n) return;
    float c = (float)(deg[i] + 1);   // +1 self loop
    dinv[i] = 1.0f / sqrtf(c);
}

// ---------------- exclusive scan (3 kernels) ----------------
__global__ __launch_bounds__(1024) void k_scan1(const int* __restrict__ deg,
                                                int* __restrict__ rowptr,
                                                int* __restrict__ bsum, int n) {
    __shared__ int tmp[1024];
    int tid = threadIdx.x;
    int i = blockIdx.x * 1024 + tid;
    int v = (i < n) ? deg[i] : 0;
    tmp[tid] = v;
    __syncthreads();
    for (int off = 1; off < 1024; off <<= 1) {
        int t = (tid >= off) ? tmp[tid - off] : 0;
        __syncthreads();
        tmp[tid] += t;
        __syncthreads();
    }
    if (i < n) rowptr[i] = tmp[tid] - v;          // exclusive
    if (tid == 1023) bsum[blockIdx.x] = tmp[1023];
}

__global__ __launch_bounds__(128) void k_scan2(int* __restrict__ bsum, int nb) {
    __shared__ int tmp[128];
    int tid = threadIdx.x;
    int v = (tid < nb) ? bsum[tid] : 0;
    tmp[tid] = v;
    __syncthreads();
    for (int off = 1; off < 128; off <<= 1) {
        int t = (tid >= off) ? tmp[tid - off] : 0;
        __syncthreads();
        tmp[tid] += t;
        __syncthreads();
    }
    if (tid < nb) bsum[tid] = tmp[tid] - v;       // exclusive block offsets
}

__global__ __launch_bounds__(1024) void k_scan3(int* __restrict__ rowptr, int* __restrict__ cur,
                                                const int* __restrict__ bsum, int n) {
    int i = blockIdx.x * 1024 + threadIdx.x;
    if (i >= n) return;
    int r = rowptr[i] + bsum[blockIdx.x];
    rowptr[i] = r;
    cur[i] = r;
}

// ---------------- CSR fill (dst-grouped src list) ----------------
__global__ void k_fill(const int* __restrict__ ei, int* __restrict__ cur,
                       int* __restrict__ col, int E) {
    int e = blockIdx.x * 256 + threadIdx.x;
    if (e >= E) return;
    int s = ei[e], d = ei[E + e];
    int pos = atomicAdd(&cur[d], 1);
    col[pos] = s;
}

// ---------------- transpose + cvt: src f32 [K,N] -> dst f16 [N,K] ----------------
template <int K, int N>
__global__ void k_prept(const float* __restrict__ src, _Float16* __restrict__ dst) {
    int i = blockIdx.x * 256 + threadIdx.x;
    if (i >= K * N) return;
    int nn = i / K, kk = i % K;
    dst[i] = (_Float16)src[kk * N + nn];
}

// ---------------- MFMA matmul + dinv scale: O_f16[M,N] = (X[M,K] @ W[K,N]) * dinv[m] ----------------
// WT is f16 [N][K]. X is f32 (XF32=true) or f16. No LDS; A-frags direct from global.
// Fragment layouts (HW-validated by k_predm): A row=lane&15, k=(lane>>4)*8+j;
// B col=lane&15, same k; C/D col=lane&15, row=(lane>>4)*4+reg.
template <int N, int K, bool XF32>
__global__ __launch_bounds__(256) void k_mmf(const void* __restrict__ Xv,
                                             const _Float16* __restrict__ WT,
                                             const float* __restrict__ dinv,
                                             _Float16* __restrict__ O, int M) {
    int tid = threadIdx.x;
    int wid = tid >> 6, lane = tid & 63;
    int lr = lane & 15, kg = lane >> 4;
    int row0 = blockIdx.x * 64 + wid * 16;
    int arow = min(row0 + lr, M - 1);
    const int NF = N / 16;
    f32x4 acc[NF];
#pragma unroll
    for (int nr = 0; nr < NF; nr++) acc[nr] = (f32x4){0.f, 0.f, 0.f, 0.f};

#pragma unroll
    for (int ks = 0; ks < K / 32; ks++) {
        half8 a;
        if (XF32) {
            const float* Xf = (const float*)Xv + (size_t)arow * K + ks * 32 + kg * 8;
            float4 x0 = *(const float4*)Xf;
            float4 x1 = *(const float4*)(Xf + 4);
            a[0] = (_Float16)x0.x; a[1] = (_Float16)x0.y;
            a[2] = (_Float16)x0.z; a[3] = (_Float16)x0.w;
            a[4] = (_Float16)x1.x; a[5] = (_Float16)x1.y;
            a[6] = (_Float16)x1.z; a[7] = (_Float16)x1.w;
        } else {
            a = *(const half8*)((const _Float16*)Xv + (size_t)arow * K + ks * 32 + kg * 8);
        }
#pragma unroll
        for (int nr = 0; nr < NF; nr++) {
            half8 b = *(const half8*)&WT[(size_t)(nr * 16 + lr) * K + ks * 32 + kg * 8];
            acc[nr] = __builtin_amdgcn_mfma_f32_16x16x32_f16(a, b, acc[nr], 0, 0, 0);
        }
    }

    int orow0 = row0 + kg * 4;
    float dv[4];
#pragma unroll
    for (int r = 0; r < 4; r++) dv[r] = dinv[min(orow0 + r, M - 1)];
#pragma unroll
    for (int nr = 0; nr < NF; nr++)
#pragma unroll
        for (int r = 0; r < 4; r++) {
            int orow = orow0 + r;
            if (orow < M)
                O[(size_t)orow * N + nr * 16 + lr] = (_Float16)(acc[nr][r] * dv[r]);
        }
}

// ---------------- gather aggregation over pre-scaled f16 rows ----------------
// O[d] = act( dinv[d] * ( Hs[d] + sum_{s in N(d)} Hs[s] ) + b ),  Hs = (XW)*dinv f16
template <int C, bool RELU, typename OT>
__global__ __launch_bounds__(256) void k_gath(const _Float16* __restrict__ Hs,
                                              const float* __restrict__ dinv,
                                              const int* __restrict__ rowptr,
                                              const int* __restrict__ deg,
                                              const int* __restrict__ col,
                                              const float* __restrict__ b,
                                              OT* __restrict__ O, int n) {
    const int TPN = C / 2;                  // lanes per node, half2 each
    const int NPB = 256 / TPN;
    int node = blockIdx.x * NPB + threadIdx.x / TPN;
    int lane2 = threadIdx.x % TPN;
    if (node >= n) return;
    int start = rowptr[node];
    int cnt = deg[node];
    float dd = dinv[node];

    half2v hself = *(const half2v*)&Hs[(size_t)node * C + lane2 * 2];
    float ax = (float)hself[0], ay = (float)hself[1];

    for (int base = 0; base < cnt; base += TPN) {
        int m = min(cnt - base, TPN);
        int myc = (lane2 < m) ? col[start + base + lane2] : 0;
        int j = 0;
        for (; j + 1 < m; j += 2) {
            int s0 = __shfl(myc, j, TPN);
            int s1 = __shfl(myc, j + 1, TPN);
            half2v h0 = *(const half2v*)&Hs[(size_t)s0 * C + lane2 * 2];
            half2v h1 = *(const half2v*)&Hs[(size_t)s1 * C + lane2 * 2];
            ax += (float)h0[0] + (float)h1[0];
            ay += (float)h0[1] + (float)h1[1];
        }
        if (j < m) {
            int s0 = __shfl(myc, j, TPN);
            half2v h0 = *(const half2v*)&Hs[(size_t)s0 * C + lane2 * 2];
            ax += (float)h0[0];
            ay += (float)h0[1];
        }
    }

    float2 bb = ((const float2*)b)[lane2];
    float vx = ax * dd + bb.x;
    float vy = ay * dd + bb.y;
    if (RELU) { vx = fmaxf(vx, 0.f); vy = fmaxf(vy, 0.f); }
    if constexpr (sizeof(OT) == 2) {
        half2v o; o[0] = (_Float16)vx; o[1] = (_Float16)vy;
        *(half2v*)&((_Float16*)O)[(size_t)node * C + lane2 * 2] = o;
    } else {
        ((float2*)((float*)O + (size_t)node * C))[lane2] = make_float2(vx, vy);
    }
}

// ---------------- MFMA link-prediction head (unchanged, validated) ----------------
__global__ __launch_bounds__(256) void k_predm(const float* __restrict__ Z,      // [NODES,64] f32
                                               const int* __restrict__ eli,      // [2,P]
                                               const _Float16* __restrict__ WT,  // [256n][256k]
                                               const float* __restrict__ bm1,
                                               const float* __restrict__ Wm2,
                                               const float* __restrict__ bm2,
                                               float* __restrict__ out, int P) {
    __shared__ _Float16 pf[64][264];   // ~33.8 KB
    __shared__ float red[4][64];
    int tid = threadIdx.x;
    int p0 = blockIdx.x * 64;

    {
        int pr = tid >> 2, q = tid & 3;       // 4 threads/pair, 16 cols each
        int pg = p0 + pr;
        int s = 0, d = 0;
        if (pg < P) { s = eli[pg]; d = eli[P + pg]; }
        const float4* zs4 = (const float4*)(Z + (size_t)s * 64 + q * 16);
        const float4* zd4 = (const float4*)(Z + (size_t)d * 64 + q * 16);
#pragma unroll
        for (int j = 0; j < 4; ++j) {
            float4 a = zs4[j], b = zd4[j];
            int c = q * 16 + j * 4;
            pf[pr][c + 0] = (_Float16)a.x;
            pf[pr][c + 1] = (_Float16)a.y;
            pf[pr][c + 2] = (_Float16)a.z;
            pf[pr][c + 3] = (_Float16)a.w;
            pf[pr][64 + c + 0] = (_Float16)b.x;
            pf[pr][64 + c + 1] = (_Float16)b.y;
            pf[pr][64 + c + 2] = (_Float16)b.z;
            pf[pr][64 + c + 3] = (_Float16)b.w;
            pf[pr][128 + c + 0] = (_Float16)(a.x * b.x);
            pf[pr][128 + c + 1] = (_Float16)(a.y * b.y);
            pf[pr][128 + c + 2] = (_Float16)(a.z * b.z);
            pf[pr][128 + c + 3] = (_Float16)(a.w * b.w);
            pf[pr][192 + c + 0] = (_Float16)fabsf(a.x - b.x);
            pf[pr][192 + c + 1] = (_Float16)fabsf(a.y - b.y);
            pf[pr][192 + c + 2] = (_Float16)fabsf(a.z - b.z);
            pf[pr][192 + c + 3] = (_Float16)fabsf(a.w - b.w);
        }
    }
    __syncthreads();

    int wid = tid >> 6, lane = tid & 63;
    int lr = lane & 15, kg = lane >> 4;
    int n0 = wid * 64;

    float wmv[4], bmv[4];
#pragma unroll
    for (int nr = 0; nr < 4; nr++) {
        int nn = n0 + nr * 16 + lr;
        wmv[nr] = Wm2[nn];
        bmv[nr] = bm1[nn];
    }

    f32x4 acc[4][4];
#pragma unroll
    for (int mr = 0; mr < 4; mr++)
#pragma unroll
        for (int nr = 0; nr < 4; nr++) acc[mr][nr] = (f32x4){0.f, 0.f, 0.f, 0.f};

    for (int ks = 0; ks < 8; ks++) {
        half8 a[4], b[4];
#pragma unroll
        for (int mr = 0; mr < 4; mr++)
            a[mr] = *(const half8*)&pf[mr * 16 + lr][ks * 32 + kg * 8];
#pragma unroll
        for (int nr = 0; nr < 4; nr++)
            b[nr] = *(const half8*)&WT[(size_t)(n0 + nr * 16 + lr) * 256 + ks * 32 + kg * 8];
#pragma unroll
        for (int mr = 0; mr < 4; mr++)
#pragma unroll
            for (int nr = 0; nr < 4; nr++)
                acc[mr][nr] = __builtin_amdgcn_mfma_f32_16x16x32_f16(a[mr], b[nr], acc[mr][nr], 0, 0, 0);
    }

#pragma unroll
    for (int mr = 0; mr < 4; mr++) {
#pragma unroll
        for (int reg = 0; reg < 4; reg++) {
            float p = 0.f;
#pragma unroll
            for (int nr = 0; nr < 4; nr++)
                p += fmaxf(acc[mr][nr][reg] + bmv[nr], 0.f) * wmv[nr];
            p += __shfl_xor(p, 1);
            p += __shfl_xor(p, 2);
            p += __shfl_xor(p, 4);
            p += __shfl_xor(p, 8);
            if (lr == 0) red[wid][mr * 16 + kg * 4 + reg] = p;
        }
    }
    __syncthreads();
    if (tid < 64) {
        int pg = p0 + tid;
        if (pg < P)
            out[pg] = red[0][tid] + red[1][tid] + red[2][tid] + red[3][tid] + bm2[0];
    }
}

extern "C" void kernel_launch(void* const* d_in, const int* in_sizes, int n_in,
                              void* d_out, int out_size, void* d_ws, size_t ws_size,
                              hipStream_t stream) {
    const float* x   = (const float*)d_in[0];
    const int*   ei  = (const int*)d_in[1];
    const int*   eli = (const int*)d_in[2];
    const float* W1  = (const float*)d_in[3];
    const float* b1  = (const float*)d_in[4];
    const float* W2  = (const float*)d_in[5];
    const float* b2  = (const float*)d_in[6];
    const float* Wm1 = (const float*)d_in[7];
    const float* bm1 = (const float*)d_in[8];
    const float* Wm2 = (const float*)d_in[9];
    const float* bm2 = (const float*)d_in[10];
    float* out = (float*)d_out;

    const int n = NODES;
    const int E = in_sizes[1] / 2;
    const int P = in_sizes[2] / 2;

    char* ws = (char*)d_ws;
    size_t off = 0;
    auto alloc = [&](size_t bytes) {
        size_t o = off;
        off += (bytes + 255) & ~(size_t)255;
        return o;
    };
    int*      deg    = (int*)(ws + alloc((size_t)n * 4));
    int*      rowptr = (int*)(ws + alloc((size_t)n * 4));
    int*      cur    = (int*)(ws + alloc((size_t)n * 4));
    int*      colx   = (int*)(ws + alloc((size_t)E * 4));
    int*      bsum   = (int*)(ws + alloc(512 * 4));
    float*    dinv   = (float*)(ws + alloc((size_t)n * 4));
    _Float16* WmT    = (_Float16*)(ws + alloc((size_t)256 * 256 * 2));
    _Float16* W1T    = (_Float16*)(ws + alloc((size_t)128 * 128 * 2));
    _Float16* W2T    = (_Float16*)(ws + alloc((size_t)64 * 128 * 2));
    _Float16* Hs1    = (_Float16*)(ws + alloc((size_t)n * HIDC * 2));  // (x@W1)*dinv f16
    _Float16* C1     = (_Float16*)(ws + alloc((size_t)n * HIDC * 2));  // conv1 out f16
    _Float16* Hs2    = (_Float16*)(ws + alloc((size_t)n * EMBC * 2));  // (C1@W2)*dinv f16
    float*    Z      = (float*)(ws + alloc((size_t)n * EMBC * 4));     // conv2 out f32

    // ---- CSR build + weight prep ----
    hipMemsetAsync(deg, 0, (size_t)n * 4, stream);
    k_deg<<<(E + 255) / 256, 256, 0, stream>>>(ei, deg, E);
    k_prept<256, 256><<<(256 * 256 + 255) / 256, 256, 0, stream>>>(Wm1, WmT);
    k_prept<128, 128><<<(128 * 128 + 255) / 256, 256, 0, stream>>>(W1, W1T);
    k_prept<128, 64><<<(128 * 64 + 255) / 256, 256, 0, stream>>>(W2, W2T);
    int nb = (n + 1023) / 1024;
    k_scan1<<<nb, 1024, 0, stream>>>(deg, rowptr, bsum, n);
    k_scan2<<<1, 128, 0, stream>>>(bsum, nb);
    k_scan3<<<nb, 1024, 0, stream>>>(rowptr, cur, bsum, n);
    k_fill<<<(E + 255) / 256, 256, 0, stream>>>(ei, cur, colx, E);
    k_dinv<<<(n + 255) / 256, 256, 0, stream>>>(deg, dinv, n);

    int mmGrid = (n + 63) / 64;

    // ---- conv1: Hs1 = (x@W1)*dinv ; C1 = relu(dinv*(Hs1[d]+sum Hs1[s]) + b1) ----
    k_mmf<HIDC, INC, true><<<mmGrid, 256, 0, stream>>>(x, W1T, dinv, Hs1, n);
    {
        const int NPB = 256 / (HIDC / 2);   // 4 nodes/block
        k_gath<HIDC, true, _Float16><<<(n + NPB - 1) / NPB, 256, 0, stream>>>(
            Hs1, dinv, rowptr, deg, colx, b1, C1, n);
    }

    // ---- conv2: Hs2 = (C1@W2)*dinv ; Z = dinv*(Hs2[d]+sum Hs2[s]) + b2 ----
    k_mmf<EMBC, HIDC, false><<<mmGrid, 256, 0, stream>>>(C1, W2T, dinv, Hs2, n);
    {
        const int NPB = 256 / (EMBC / 2);   // 8 nodes/block
        k_gath<EMBC, false, float><<<(n + NPB - 1) / NPB, 256, 0, stream>>>(
            Hs2, dinv, rowptr, deg, colx, b2, Z, n);
    }

    // ---- prediction head (MFMA f16) ----
    k_predm<<<(P + 63) / 64, 256, 0, stream>>>(Z, eli, WmT, bm1, Wm2, bm2, out, P);
}